// Round 2
// baseline (828.555 us; speedup 1.0000x reference)
//
#include <hip/hip_runtime.h>
#include <hip/hip_bf16.h>
#include <stdint.h>

// Problem constants (match reference)
#define B_SZ   16384
#define IN_DIM 1024
#define H1     2048
#define H2     2048
#define HID    1024
#define SPEC_H 2048
#define NE     8
#define CHUNK  4096     // encoder batch chunk (4 chunks) to bound workspace
#define MAX_TILES 136   // floor(B/128) + NE padded tiles upper bound

typedef __bf16 bf16x8 __attribute__((ext_vector_type(8)));
typedef float  f32x4  __attribute__((ext_vector_type(4)));

__device__ __forceinline__ ushort f2bf(float f) {
  // round-to-nearest-even fp32 -> bf16
  uint32_t u = __float_as_uint(f);
  u += 0x7FFF + ((u >> 16) & 1);
  return (ushort)(u >> 16);
}

__device__ __forceinline__ void gl_lds16(const void* g, void* l) {
  // async global->LDS, 16B per lane; LDS dest = wave-uniform base + lane*16
  __builtin_amdgcn_global_load_lds(
      (const __attribute__((address_space(1))) void*)g,
      (__attribute__((address_space(3))) void*)l, 16, 0, 0);
}

// ---------------- elementwise / transpose-cast ----------------

__global__ void cast_f32_bf16(const float* __restrict__ in,
                              ushort* __restrict__ out, int n) {
  int i = (blockIdx.x * 256 + threadIdx.x) * 4;
  if (i + 3 < n) {
    float4 v = *(const float4*)(in + i);
    ushort4 o;
    o.x = f2bf(v.x); o.y = f2bf(v.y); o.z = f2bf(v.z); o.w = f2bf(v.w);
    *(ushort4*)(out + i) = o;
  }
}

// in: [batch][K][N] fp32 (row-major) -> out: [batch][N][K] bf16
__global__ void transpose_cast(const float* __restrict__ in,
                               ushort* __restrict__ out, int K, int N) {
  __shared__ float tile[64][65];
  int n0 = blockIdx.x * 64, k0 = blockIdx.y * 64;
  const float* src = in + (size_t)blockIdx.z * K * N;
  ushort* dst = out + (size_t)blockIdx.z * K * N;
  int tx = threadIdx.x & 63, ty = threadIdx.x >> 6;
#pragma unroll
  for (int i = ty; i < 64; i += 4)
    tile[i][tx] = src[(size_t)(k0 + i) * N + n0 + tx];
  __syncthreads();
#pragma unroll
  for (int i = ty; i < 64; i += 4)
    dst[(size_t)(n0 + i) * K + k0 + tx] = f2bf(tile[tx][i]);
}

// ---------------- routing (counting sort by expert) ----------------

__global__ void count_k(const int* __restrict__ d, int* __restrict__ counts) {
  int i = blockIdx.x * 256 + threadIdx.x;
  if (i < B_SZ) atomicAdd(&counts[d[i]], 1);
}

__global__ void build_k(const int* __restrict__ counts, int* __restrict__ catalog,
                        int* __restrict__ poff, int* __restrict__ cursors) {
  if (threadIdx.x == 0) {
    int off = 0;  // in tiles
    for (int e = 0; e < NE; ++e) {
      poff[e] = off * 128;
      int nt = (counts[e] + 127) >> 7;
      for (int i = 0; i < nt; ++i) catalog[off + i] = e;
      off += nt;
      cursors[e] = 0;
    }
    for (int i = off; i < MAX_TILES; ++i) catalog[i] = -1;
  }
}

__global__ void scatter_k(const int* __restrict__ d, const int* __restrict__ poff,
                          int* __restrict__ cursors, int* __restrict__ perm) {
  int i = blockIdx.x * 256 + threadIdx.x;
  if (i < B_SZ) {
    int e = d[i];
    int p = atomicAdd(&cursors[e], 1);
    perm[poff[e] + p] = i;
  }
}

__global__ void init_out_k(const int* __restrict__ d, const float* __restrict__ b2,
                           float* __restrict__ out) {
  int i = blockIdx.x * 256 + threadIdx.x;
  if (i < B_SZ) out[i] = b2[d[i]];  // spec_b2[e][0]
}

// ---------------- m97-style bf16 GEMM: C = act(A @ Bt^T + bias) ----------------
// A: [M][K] bf16, Bt: [N][K] bf16, C: [M][N] bf16. 128x128 tile, BK=64,
// 256 thr = 4 waves in 2x2, each wave 64x64 via 4x4 mfma_f32_16x16x32_bf16.
// LDS rows XOR-swizzled in 16B chunks so frag ds_read_b128 is 2-way (free).

template <int RELU>
__global__ __launch_bounds__(256, 2) void gemm_bias(
    const ushort* __restrict__ A, const ushort* __restrict__ Bt,
    const float* __restrict__ bias, ushort* __restrict__ C,
    int M, int N, int K) {
  __shared__ __align__(16) ushort lA[128 * 64];
  __shared__ __align__(16) ushort lB[128 * 64];
  const int t = threadIdx.x;
  const int m0 = blockIdx.y * 128, n0 = blockIdx.x * 128;
  const int w = t >> 6, lane = t & 63;
  const int wm = (w >> 1) * 64, wn = (w & 1) * 64;
  const int q = lane >> 4, rl = lane & 15;

  f32x4 acc[4][4];
#pragma unroll
  for (int mi = 0; mi < 4; ++mi)
#pragma unroll
    for (int ni = 0; ni < 4; ++ni) acc[mi][ni] = 0.0f;

  const int row_s = t >> 3;  // staging row within 32-row round
  const int pch_s = t & 7;   // physical 16B chunk within row

  for (int k0 = 0; k0 < K; k0 += 64) {
    __syncthreads();
#pragma unroll
    for (int j = 0; j < 4; ++j) {
      int row = j * 32 + row_s;
      int gch = pch_s ^ (row & 7);
      gl_lds16(A + (size_t)(m0 + row) * K + k0 + gch * 8, lA + j * 2048 + w * 512);
      gl_lds16(Bt + (size_t)(n0 + row) * K + k0 + gch * 8, lB + j * 2048 + w * 512);
    }
    __syncthreads();
#pragma unroll
    for (int kk = 0; kk < 2; ++kk) {
      bf16x8 af[4], bfr[4];
#pragma unroll
      for (int i = 0; i < 4; ++i) {
        int pc = (kk * 4 + q) ^ (rl & 7);
        af[i]  = __builtin_bit_cast(bf16x8, *(const int4*)(lA + (wm + i * 16 + rl) * 64 + pc * 8));
        bfr[i] = __builtin_bit_cast(bf16x8, *(const int4*)(lB + (wn + i * 16 + rl) * 64 + pc * 8));
      }
#pragma unroll
      for (int mi = 0; mi < 4; ++mi)
#pragma unroll
        for (int ni = 0; ni < 4; ++ni)
          acc[mi][ni] = __builtin_amdgcn_mfma_f32_16x16x32_bf16(af[mi], bfr[ni], acc[mi][ni], 0, 0, 0);
    }
  }

  // epilogue: C/D layout col=lane&15, row=(lane>>4)*4+reg (m89-verified)
  float bv[4];
#pragma unroll
  for (int ni = 0; ni < 4; ++ni) bv[ni] = bias[n0 + wn + ni * 16 + rl];
#pragma unroll
  for (int mi = 0; mi < 4; ++mi) {
    int rg = m0 + wm + mi * 16 + q * 4;
#pragma unroll
    for (int r = 0; r < 4; ++r) {
#pragma unroll
      for (int ni = 0; ni < 4; ++ni) {
        float v = acc[mi][ni][r] + bv[ni];
        if (RELU) v = fmaxf(v, 0.0f);
        C[(size_t)(rg + r) * N + n0 + wn + ni * 16 + rl] = f2bf(v);
      }
    }
  }
}

// ---------------- fused expert stage ----------------
// Block = (row-tile of 128 gathered rows of one expert) x (128-col chunk of SPEC_H).
// Computes h = relu(Z[rows] @ W1t[e]^T + b1[e]) for its 128x128 tile in regs,
// immediately reduces y_partial = h . w2[e][cols], atomicAdds into out[rows].
__global__ __launch_bounds__(256, 2) void expert_fused(
    const ushort* __restrict__ Z, const ushort* __restrict__ W1t,
    const float* __restrict__ b1, const float* __restrict__ w2,
    const int* __restrict__ perm, const int* __restrict__ catalog,
    float* __restrict__ out) {
  int e = catalog[blockIdx.x];
  if (e < 0) return;
  __shared__ __align__(16) ushort lA[128 * 64];
  __shared__ __align__(16) ushort lB[128 * 64];
  __shared__ int perml[128];
  __shared__ float ysum[128];
  const int t = threadIdx.x;
  if (t < 128) {
    perml[t] = perm[blockIdx.x * 128 + t];
    ysum[t] = 0.0f;
  }
  __syncthreads();

  const int n0 = blockIdx.y * 128;
  const ushort* Bt = W1t + (size_t)e * SPEC_H * HID;
  const float* b1e = b1 + (size_t)e * SPEC_H;
  const float* w2e = w2 + (size_t)e * SPEC_H;
  const int w = t >> 6, lane = t & 63;
  const int wm = (w >> 1) * 64, wn = (w & 1) * 64;
  const int q = lane >> 4, rl = lane & 15;

  f32x4 acc[4][4];
#pragma unroll
  for (int mi = 0; mi < 4; ++mi)
#pragma unroll
    for (int ni = 0; ni < 4; ++ni) acc[mi][ni] = 0.0f;

  const int row_s = t >> 3;
  const int pch_s = t & 7;

  for (int k0 = 0; k0 < HID; k0 += 64) {
    __syncthreads();
#pragma unroll
    for (int j = 0; j < 4; ++j) {
      int row = j * 32 + row_s;
      int gch = pch_s ^ (row & 7);
      int zr = perml[row];
      zr = zr < 0 ? 0 : zr;  // pad rows read row 0; discarded later
      gl_lds16(Z + (size_t)zr * HID + k0 + gch * 8, lA + j * 2048 + w * 512);
      gl_lds16(Bt + (size_t)(n0 + row) * HID + k0 + gch * 8, lB + j * 2048 + w * 512);
    }
    __syncthreads();
#pragma unroll
    for (int kk = 0; kk < 2; ++kk) {
      bf16x8 af[4], bfr[4];
#pragma unroll
      for (int i = 0; i < 4; ++i) {
        int pc = (kk * 4 + q) ^ (rl & 7);
        af[i]  = __builtin_bit_cast(bf16x8, *(const int4*)(lA + (wm + i * 16 + rl) * 64 + pc * 8));
        bfr[i] = __builtin_bit_cast(bf16x8, *(const int4*)(lB + (wn + i * 16 + rl) * 64 + pc * 8));
      }
#pragma unroll
      for (int mi = 0; mi < 4; ++mi)
#pragma unroll
        for (int ni = 0; ni < 4; ++ni)
          acc[mi][ni] = __builtin_amdgcn_mfma_f32_16x16x32_bf16(af[mi], bfr[ni], acc[mi][ni], 0, 0, 0);
    }
  }

  // epilogue: h = relu(acc + b1), partial y = sum_n h * w2
  float w2v[4], b1v[4];
#pragma unroll
  for (int ni = 0; ni < 4; ++ni) {
    int n = n0 + wn + ni * 16 + rl;
    w2v[ni] = w2e[n];
    b1v[ni] = b1e[n];
  }
#pragma unroll
  for (int mi = 0; mi < 4; ++mi) {
#pragma unroll
    for (int r = 0; r < 4; ++r) {
      float p = 0.0f;
#pragma unroll
      for (int ni = 0; ni < 4; ++ni) {
        float h = acc[mi][ni][r] + b1v[ni];
        h = fmaxf(h, 0.0f);
        p += h * w2v[ni];
      }
      // reduce across the 16 lanes holding the 16 cols of this row
      p += __shfl_xor(p, 1);
      p += __shfl_xor(p, 2);
      p += __shfl_xor(p, 4);
      p += __shfl_xor(p, 8);
      if (rl == 0) atomicAdd(&ysum[wm + mi * 16 + q * 4 + r], p);
    }
  }
  __syncthreads();
  if (t < 128) {
    int orow = perml[t];
    if (orow >= 0) atomicAdd(&out[orow], ysum[t]);
  }
}

// ---------------- host ----------------

extern "C" void kernel_launch(void* const* d_in, const int* in_sizes, int n_in,
                              void* d_out, int out_size, void* d_ws, size_t ws_size,
                              hipStream_t stream) {
  const float* x   = (const float*)d_in[0];
  const int*   d   = (const int*)d_in[1];
  const float* eW0 = (const float*)d_in[2];
  const float* eb0 = (const float*)d_in[3];
  const float* eW1 = (const float*)d_in[4];
  const float* eb1 = (const float*)d_in[5];
  const float* eW2 = (const float*)d_in[6];
  const float* eb2 = (const float*)d_in[7];
  const float* sW1 = (const float*)d_in[8];
  const float* sb1 = (const float*)d_in[9];
  const float* sW2 = (const float*)d_in[10];
  const float* sb2 = (const float*)d_in[11];
  float* out = (float*)d_out;

  // workspace layout (~120.1 MiB total; chunked encoder keeps it small)
  char* p = (char*)d_ws;
  ushort* W0t  = (ushort*)p; p += (size_t)IN_DIM * H1 * 2;        //  4 MiB
  ushort* W1t  = (ushort*)p; p += (size_t)H1 * H2 * 2;            //  8 MiB
  ushort* W2t  = (ushort*)p; p += (size_t)H2 * HID * 2;           //  4 MiB
  ushort* sW1t = (ushort*)p; p += (size_t)NE * HID * SPEC_H * 2;  // 32 MiB
  ushort* Zb   = (ushort*)p; p += (size_t)B_SZ * HID * 2;         // 32 MiB
  ushort* xb_c = (ushort*)p; p += (size_t)CHUNK * IN_DIM * 2;     //  8 MiB
  ushort* z1_c = (ushort*)p; p += (size_t)CHUNK * H1 * 2;         // 16 MiB
  ushort* z2_c = (ushort*)p; p += (size_t)CHUNK * H2 * 2;         // 16 MiB
  int* counts  = (int*)p; p += 64;
  int* cursors = (int*)p; p += 64;
  int* poff    = (int*)p; p += 64;
  int* catalog = (int*)p; p += 1024;                    // >= MAX_TILES ints (fixed)
  int* perm    = (int*)p; p += (size_t)MAX_TILES * 128 * 4;

  hipMemsetAsync(counts, 0, 64, stream);
  hipMemsetAsync(perm, 0xFF, (size_t)MAX_TILES * 128 * 4, stream);  // -1 = pad

  // weight transposes to bf16 [N][K] (once)
  transpose_cast<<<dim3(H1 / 64, IN_DIM / 64, 1), 256, 0, stream>>>(eW0, W0t, IN_DIM, H1);
  transpose_cast<<<dim3(H2 / 64, H1 / 64, 1), 256, 0, stream>>>(eW1, W1t, H1, H2);
  transpose_cast<<<dim3(HID / 64, H2 / 64, 1), 256, 0, stream>>>(eW2, W2t, H2, HID);
  transpose_cast<<<dim3(SPEC_H / 64, HID / 64, NE), 256, 0, stream>>>(sW1, sW1t, HID, SPEC_H);

  // routing (independent of encoder; cheap)
  count_k<<<B_SZ / 256, 256, 0, stream>>>(d, counts);
  build_k<<<1, 64, 0, stream>>>(counts, catalog, poff, cursors);
  scatter_k<<<B_SZ / 256, 256, 0, stream>>>(d, poff, cursors, perm);
  init_out_k<<<B_SZ / 256, 256, 0, stream>>>(d, sb2, out);

  // chunked encoder: x -> z1 -> z2 -> Zb, reusing per-chunk buffers
  for (int c = 0; c < B_SZ; c += CHUNK) {
    cast_f32_bf16<<<(CHUNK * IN_DIM) / 1024, 256, 0, stream>>>(
        x + (size_t)c * IN_DIM, xb_c, CHUNK * IN_DIM);
    gemm_bias<1><<<dim3(H1 / 128, CHUNK / 128), 256, 0, stream>>>(
        xb_c, W0t, eb0, z1_c, CHUNK, H1, IN_DIM);
    gemm_bias<1><<<dim3(H2 / 128, CHUNK / 128), 256, 0, stream>>>(
        z1_c, W1t, eb1, z2_c, CHUNK, H2, H1);
    gemm_bias<0><<<dim3(HID / 128, CHUNK / 128), 256, 0, stream>>>(
        z2_c, W2t, eb2, Zb + (size_t)c * HID, CHUNK, HID, H2);
  }

  // fused expert stage on full routed batch
  expert_fused<<<dim3(MAX_TILES, SPEC_H / 128), 256, 0, stream>>>(
      Zb, sW1t, sb1, sW2, perm, catalog, out);
}

// Round 3
// 725.984 us; speedup vs baseline: 1.1413x; 1.1413x over previous
//
#include <hip/hip_runtime.h>
#include <hip/hip_bf16.h>
#include <stdint.h>

// Problem constants (match reference)
#define B_SZ   16384
#define IN_DIM 1024
#define H1     2048
#define H2     2048
#define HID    1024
#define SPEC_H 2048
#define NE     8
#define MAX_TILES 136   // floor(B/128) + NE padded tiles upper bound

typedef __bf16 bf16x8 __attribute__((ext_vector_type(8)));
typedef float  f32x4  __attribute__((ext_vector_type(4)));

__device__ __forceinline__ ushort f2bf(float f) {
  // round-to-nearest-even fp32 -> bf16
  uint32_t u = __float_as_uint(f);
  u += 0x7FFF + ((u >> 16) & 1);
  return (ushort)(u >> 16);
}

__device__ __forceinline__ void gl_lds16(const void* g, void* l) {
  // async global->LDS, 16B per lane; LDS dest = wave-uniform base + lane*16
  __builtin_amdgcn_global_load_lds(
      (const __attribute__((address_space(1))) void*)g,
      (__attribute__((address_space(3))) void*)l, 16, 0, 0);
}

// ---------------- elementwise / transpose-cast ----------------

__global__ void cast_f32_bf16(const float* __restrict__ in,
                              ushort* __restrict__ out, int n) {
  int i = (blockIdx.x * 256 + threadIdx.x) * 4;
  if (i + 3 < n) {
    float4 v = *(const float4*)(in + i);
    ushort4 o;
    o.x = f2bf(v.x); o.y = f2bf(v.y); o.z = f2bf(v.z); o.w = f2bf(v.w);
    *(ushort4*)(out + i) = o;
  }
}

// in: [batch][K][N] fp32 (row-major) -> out: [batch][N][K] bf16
// Global side fully vectorized (float4 loads / ushort4 stores); LDS round-trip
// is scalar through a [64][65] tile (all accesses <=2-way banked -> free).
__global__ void transpose_cast(const float* __restrict__ in,
                               ushort* __restrict__ out, int K, int N) {
  __shared__ float tile[64][65];  // tile[n][k]
  int n0 = blockIdx.x * 64, k0 = blockIdx.y * 64;
  const float* src = in + (size_t)blockIdx.z * K * N;
  ushort* dst = out + (size_t)blockIdx.z * K * N;
  int t = threadIdx.x;
  int lk = t >> 4;           // 0..15 (k-row per pass)
  int ln4 = (t & 15) * 4;    // n-quad
#pragma unroll
  for (int j = 0; j < 4; ++j) {
    int k = lk + j * 16;
    float4 v = *(const float4*)(src + (size_t)(k0 + k) * N + n0 + ln4);
    tile[ln4 + 0][k] = v.x;
    tile[ln4 + 1][k] = v.y;
    tile[ln4 + 2][k] = v.z;
    tile[ln4 + 3][k] = v.w;
  }
  __syncthreads();
  int kc = (t & 15) * 4;     // k-quad
  int nb = t >> 4;           // 0..15
#pragma unroll
  for (int j = 0; j < 4; ++j) {
    int nn = nb + j * 16;
    ushort4 o;
    o.x = f2bf(tile[nn][kc + 0]);
    o.y = f2bf(tile[nn][kc + 1]);
    o.z = f2bf(tile[nn][kc + 2]);
    o.w = f2bf(tile[nn][kc + 3]);
    *(ushort4*)(dst + (size_t)(n0 + nn) * K + k0 + kc) = o;
  }
}

// ---------------- routing (counting sort by expert) ----------------

__global__ void count_k(const int* __restrict__ d, int* __restrict__ counts) {
  int i = blockIdx.x * 256 + threadIdx.x;
  if (i < B_SZ) atomicAdd(&counts[d[i]], 1);
}

__global__ void build_k(const int* __restrict__ counts, int* __restrict__ catalog,
                        int* __restrict__ poff, int* __restrict__ cursors) {
  if (threadIdx.x == 0) {
    int off = 0;  // in tiles
    for (int e = 0; e < NE; ++e) {
      poff[e] = off * 128;
      int nt = (counts[e] + 127) >> 7;
      for (int i = 0; i < nt; ++i) catalog[off + i] = e;
      off += nt;
      cursors[e] = 0;
    }
    for (int i = off; i < MAX_TILES; ++i) catalog[i] = -1;
  }
}

__global__ void scatter_k(const int* __restrict__ d, const int* __restrict__ poff,
                          int* __restrict__ cursors, int* __restrict__ perm) {
  int i = blockIdx.x * 256 + threadIdx.x;
  if (i < B_SZ) {
    int e = d[i];
    int p = atomicAdd(&cursors[e], 1);
    perm[poff[e] + p] = i;
  }
}

__global__ void init_out_k(const int* __restrict__ d, const float* __restrict__ b2,
                           float* __restrict__ out) {
  int i = blockIdx.x * 256 + threadIdx.x;
  if (i < B_SZ) out[i] = b2[d[i]];  // spec_b2[e][0]
}

// ---------------- m97-style bf16 GEMM: C = act(A @ Bt^T + bias) ----------------
// A: [M][K] bf16, Bt: [N][K] bf16, C: [M][N] bf16. 128x128 tile, BK=64,
// 256 thr = 4 waves in 2x2, each wave 64x64 via 4x4 mfma_f32_16x16x32_bf16.
// LDS rows XOR-swizzled in 16B chunks so frag ds_read_b128 is 2-way (free).

template <int RELU>
__global__ __launch_bounds__(256, 2) void gemm_bias(
    const ushort* __restrict__ A, const ushort* __restrict__ Bt,
    const float* __restrict__ bias, ushort* __restrict__ C,
    int M, int N, int K) {
  __shared__ __align__(16) ushort lA[128 * 64];
  __shared__ __align__(16) ushort lB[128 * 64];
  const int t = threadIdx.x;
  const int m0 = blockIdx.y * 128, n0 = blockIdx.x * 128;
  const int w = t >> 6, lane = t & 63;
  const int wm = (w >> 1) * 64, wn = (w & 1) * 64;
  const int q = lane >> 4, rl = lane & 15;

  f32x4 acc[4][4];
#pragma unroll
  for (int mi = 0; mi < 4; ++mi)
#pragma unroll
    for (int ni = 0; ni < 4; ++ni) acc[mi][ni] = 0.0f;

  const int row_s = t >> 3;  // staging row within 32-row round
  const int pch_s = t & 7;   // physical 16B chunk within row

  for (int k0 = 0; k0 < K; k0 += 64) {
    __syncthreads();
#pragma unroll
    for (int j = 0; j < 4; ++j) {
      int row = j * 32 + row_s;
      int gch = pch_s ^ (row & 7);
      gl_lds16(A + (size_t)(m0 + row) * K + k0 + gch * 8, lA + j * 2048 + w * 512);
      gl_lds16(Bt + (size_t)(n0 + row) * K + k0 + gch * 8, lB + j * 2048 + w * 512);
    }
    __syncthreads();
#pragma unroll
    for (int kk = 0; kk < 2; ++kk) {
      bf16x8 af[4], bfr[4];
#pragma unroll
      for (int i = 0; i < 4; ++i) {
        int pc = (kk * 4 + q) ^ (rl & 7);
        af[i]  = __builtin_bit_cast(bf16x8, *(const int4*)(lA + (wm + i * 16 + rl) * 64 + pc * 8));
        bfr[i] = __builtin_bit_cast(bf16x8, *(const int4*)(lB + (wn + i * 16 + rl) * 64 + pc * 8));
      }
#pragma unroll
      for (int mi = 0; mi < 4; ++mi)
#pragma unroll
        for (int ni = 0; ni < 4; ++ni)
          acc[mi][ni] = __builtin_amdgcn_mfma_f32_16x16x32_bf16(af[mi], bfr[ni], acc[mi][ni], 0, 0, 0);
    }
  }

  // epilogue: C/D layout col=lane&15, row=(lane>>4)*4+reg (m89-verified)
  float bv[4];
#pragma unroll
  for (int ni = 0; ni < 4; ++ni) bv[ni] = bias[n0 + wn + ni * 16 + rl];
#pragma unroll
  for (int mi = 0; mi < 4; ++mi) {
    int rg = m0 + wm + mi * 16 + q * 4;
#pragma unroll
    for (int r = 0; r < 4; ++r) {
#pragma unroll
      for (int ni = 0; ni < 4; ++ni) {
        float v = acc[mi][ni][r] + bv[ni];
        if (RELU) v = fmaxf(v, 0.0f);
        C[(size_t)(rg + r) * N + n0 + wn + ni * 16 + rl] = f2bf(v);
      }
    }
  }
}

// ---------------- fused expert stage ----------------
// Block = (row-tile of 128 gathered rows of one expert) x (128-col chunk of SPEC_H).
// Computes h = relu(Z[rows] @ W1t[e]^T + b1[e]) for its 128x128 tile in regs,
// immediately reduces y_partial = h . w2[e][cols], atomicAdds into out[rows].
__global__ __launch_bounds__(256, 2) void expert_fused(
    const ushort* __restrict__ Z, const ushort* __restrict__ W1t,
    const float* __restrict__ b1, const float* __restrict__ w2,
    const int* __restrict__ perm, const int* __restrict__ catalog,
    float* __restrict__ out) {
  int e = catalog[blockIdx.x];
  if (e < 0) return;
  __shared__ __align__(16) ushort lA[128 * 64];
  __shared__ __align__(16) ushort lB[128 * 64];
  __shared__ int perml[128];
  __shared__ float ysum[128];
  const int t = threadIdx.x;
  if (t < 128) {
    perml[t] = perm[blockIdx.x * 128 + t];
    ysum[t] = 0.0f;
  }
  __syncthreads();

  const int n0 = blockIdx.y * 128;
  const ushort* Bt = W1t + (size_t)e * SPEC_H * HID;
  const float* b1e = b1 + (size_t)e * SPEC_H;
  const float* w2e = w2 + (size_t)e * SPEC_H;
  const int w = t >> 6, lane = t & 63;
  const int wm = (w >> 1) * 64, wn = (w & 1) * 64;
  const int q = lane >> 4, rl = lane & 15;

  f32x4 acc[4][4];
#pragma unroll
  for (int mi = 0; mi < 4; ++mi)
#pragma unroll
    for (int ni = 0; ni < 4; ++ni) acc[mi][ni] = 0.0f;

  const int row_s = t >> 3;
  const int pch_s = t & 7;

  for (int k0 = 0; k0 < HID; k0 += 64) {
    __syncthreads();
#pragma unroll
    for (int j = 0; j < 4; ++j) {
      int row = j * 32 + row_s;
      int gch = pch_s ^ (row & 7);
      int zr = perml[row];
      zr = zr < 0 ? 0 : zr;  // pad rows read row 0; discarded later
      gl_lds16(Z + (size_t)zr * HID + k0 + gch * 8, lA + j * 2048 + w * 512);
      gl_lds16(Bt + (size_t)(n0 + row) * HID + k0 + gch * 8, lB + j * 2048 + w * 512);
    }
    __syncthreads();
#pragma unroll
    for (int kk = 0; kk < 2; ++kk) {
      bf16x8 af[4], bfr[4];
#pragma unroll
      for (int i = 0; i < 4; ++i) {
        int pc = (kk * 4 + q) ^ (rl & 7);
        af[i]  = __builtin_bit_cast(bf16x8, *(const int4*)(lA + (wm + i * 16 + rl) * 64 + pc * 8));
        bfr[i] = __builtin_bit_cast(bf16x8, *(const int4*)(lB + (wn + i * 16 + rl) * 64 + pc * 8));
      }
#pragma unroll
      for (int mi = 0; mi < 4; ++mi)
#pragma unroll
        for (int ni = 0; ni < 4; ++ni)
          acc[mi][ni] = __builtin_amdgcn_mfma_f32_16x16x32_bf16(af[mi], bfr[ni], acc[mi][ni], 0, 0, 0);
    }
  }

  // epilogue: h = relu(acc + b1), partial y = sum_n h * w2
  float w2v[4], b1v[4];
#pragma unroll
  for (int ni = 0; ni < 4; ++ni) {
    int n = n0 + wn + ni * 16 + rl;
    w2v[ni] = w2e[n];
    b1v[ni] = b1e[n];
  }
#pragma unroll
  for (int mi = 0; mi < 4; ++mi) {
#pragma unroll
    for (int r = 0; r < 4; ++r) {
      float p = 0.0f;
#pragma unroll
      for (int ni = 0; ni < 4; ++ni) {
        float h = acc[mi][ni][r] + b1v[ni];
        h = fmaxf(h, 0.0f);
        p += h * w2v[ni];
      }
      // reduce across the 16 lanes holding the 16 cols of this row
      p += __shfl_xor(p, 1);
      p += __shfl_xor(p, 2);
      p += __shfl_xor(p, 4);
      p += __shfl_xor(p, 8);
      if (rl == 0) atomicAdd(&ysum[wm + mi * 16 + q * 4 + r], p);
    }
  }
  __syncthreads();
  if (t < 128) {
    int orow = perml[t];
    if (orow >= 0) atomicAdd(&out[orow], ysum[t]);
  }
}

// ---------------- host ----------------

extern "C" void kernel_launch(void* const* d_in, const int* in_sizes, int n_in,
                              void* d_out, int out_size, void* d_ws, size_t ws_size,
                              hipStream_t stream) {
  const float* x   = (const float*)d_in[0];
  const int*   d   = (const int*)d_in[1];
  const float* eW0 = (const float*)d_in[2];
  const float* eb0 = (const float*)d_in[3];
  const float* eW1 = (const float*)d_in[4];
  const float* eb1 = (const float*)d_in[5];
  const float* eW2 = (const float*)d_in[6];
  const float* eb2 = (const float*)d_in[7];
  const float* sW1 = (const float*)d_in[8];
  const float* sb1 = (const float*)d_in[9];
  const float* sW2 = (const float*)d_in[10];
  const float* sb2 = (const float*)d_in[11];
  float* out = (float*)d_out;

  // Adaptive encoder chunk: pick the largest that fits ws_size.
  // Fixed part: weights bf16 (48 MiB) + Zb (32 MiB) + routing (~0.1 MiB).
  // Per-chunk: xb_c + z1_c + z2_c = CH * (1024+2048+2048)*2 = CH*10240 bytes.
  const size_t fixed = ((size_t)(4 + 8 + 4 + 32 + 32) << 20) + (1 << 20);
  int CH = 4096;
  if (ws_size >= fixed + (size_t)16384 * 10240) CH = 16384;       // ~241 MiB
  else if (ws_size >= fixed + (size_t)8192 * 10240) CH = 8192;    // ~164 MiB

  char* p = (char*)d_ws;
  ushort* W0t  = (ushort*)p; p += (size_t)IN_DIM * H1 * 2;        //  4 MiB
  ushort* W1t  = (ushort*)p; p += (size_t)H1 * H2 * 2;            //  8 MiB
  ushort* W2t  = (ushort*)p; p += (size_t)H2 * HID * 2;           //  4 MiB
  ushort* sW1t = (ushort*)p; p += (size_t)NE * HID * SPEC_H * 2;  // 32 MiB
  ushort* Zb   = (ushort*)p; p += (size_t)B_SZ * HID * 2;         // 32 MiB
  int* counts  = (int*)p; p += 64;
  int* cursors = (int*)p; p += 64;
  int* poff    = (int*)p; p += 64;
  int* catalog = (int*)p; p += 1024;                    // >= MAX_TILES ints
  int* perm    = (int*)p; p += (size_t)MAX_TILES * 128 * 4;
  p = (char*)(((uintptr_t)p + 255) & ~(uintptr_t)255);
  ushort* xb_c = (ushort*)p; p += (size_t)CH * IN_DIM * 2;
  ushort* z1_c = (ushort*)p; p += (size_t)CH * H1 * 2;
  ushort* z2_c = (ushort*)p; p += (size_t)CH * H2 * 2;

  hipMemsetAsync(counts, 0, 64, stream);
  hipMemsetAsync(perm, 0xFF, (size_t)MAX_TILES * 128 * 4, stream);  // -1 = pad

  // routing (independent of encoder; cheap)
  count_k<<<B_SZ / 256, 256, 0, stream>>>(d, counts);
  build_k<<<1, 64, 0, stream>>>(counts, catalog, poff, cursors);
  scatter_k<<<B_SZ / 256, 256, 0, stream>>>(d, poff, cursors, perm);
  init_out_k<<<B_SZ / 256, 256, 0, stream>>>(d, sb2, out);

  // weight transposes to bf16 [N][K] (once)
  transpose_cast<<<dim3(H1 / 64, IN_DIM / 64, 1), 256, 0, stream>>>(eW0, W0t, IN_DIM, H1);
  transpose_cast<<<dim3(H2 / 64, H1 / 64, 1), 256, 0, stream>>>(eW1, W1t, H1, H2);
  transpose_cast<<<dim3(HID / 64, H2 / 64, 1), 256, 0, stream>>>(eW2, W2t, H2, HID);
  transpose_cast<<<dim3(SPEC_H / 64, HID / 64, NE), 256, 0, stream>>>(sW1, sW1t, HID, SPEC_H);

  // encoder: x -> z1 -> z2 -> Zb (chunked only if workspace forces it)
  for (int c = 0; c < B_SZ; c += CH) {
    cast_f32_bf16<<<(CH * IN_DIM) / 1024, 256, 0, stream>>>(
        x + (size_t)c * IN_DIM, xb_c, CH * IN_DIM);
    gemm_bias<1><<<dim3(H1 / 128, CH / 128), 256, 0, stream>>>(
        xb_c, W0t, eb0, z1_c, CH, H1, IN_DIM);
    gemm_bias<1><<<dim3(H2 / 128, CH / 128), 256, 0, stream>>>(
        z1_c, W1t, eb1, z2_c, CH, H2, H1);
    gemm_bias<0><<<dim3(HID / 128, CH / 128), 256, 0, stream>>>(
        z2_c, W2t, eb2, Zb + (size_t)c * HID, CH, HID, H2);
  }

  // fused expert stage on full routed batch
  expert_fused<<<dim3(MAX_TILES, SPEC_H / 128), 256, 0, stream>>>(
      Zb, sW1t, sb1, sW2, perm, catalog, out);
}

// Round 4
// 696.264 us; speedup vs baseline: 1.1900x; 1.0427x over previous
//
#include <hip/hip_runtime.h>
#include <hip/hip_bf16.h>
#include <stdint.h>

// Problem constants (match reference)
#define B_SZ   16384
#define IN_DIM 1024
#define H1     2048
#define H2     2048
#define HID    1024
#define SPEC_H 2048
#define NE     8
#define MAX_TILES 136   // floor(B/128) + NE padded tiles upper bound

typedef __bf16 bf16x8 __attribute__((ext_vector_type(8)));
typedef float  f32x4  __attribute__((ext_vector_type(4)));

__device__ __forceinline__ ushort f2bf(float f) {
  // round-to-nearest-even fp32 -> bf16
  uint32_t u = __float_as_uint(f);
  u += 0x7FFF + ((u >> 16) & 1);
  return (ushort)(u >> 16);
}

__device__ __forceinline__ void gl_lds16(const void* g, void* l) {
  // async global->LDS, 16B per lane; LDS dest = wave-uniform base + lane*16
  __builtin_amdgcn_global_load_lds(
      (const __attribute__((address_space(1))) void*)g,
      (__attribute__((address_space(3))) void*)l, 16, 0, 0);
}

// ---------------- elementwise / transpose-cast ----------------

__global__ void cast_f32_bf16(const float* __restrict__ in,
                              ushort* __restrict__ out, int n) {
  int i = (blockIdx.x * 256 + threadIdx.x) * 4;
  if (i + 3 < n) {
    float4 v = *(const float4*)(in + i);
    ushort4 o;
    o.x = f2bf(v.x); o.y = f2bf(v.y); o.z = f2bf(v.z); o.w = f2bf(v.w);
    *(ushort4*)(out + i) = o;
  }
}

// in: [batch][K][N] fp32 (row-major) -> out: [batch][N][K] bf16
// Global side fully vectorized (float4 loads / ushort4 stores); LDS round-trip
// is scalar through a [64][65] tile (all accesses <=2-way banked -> free).
__global__ void transpose_cast(const float* __restrict__ in,
                               ushort* __restrict__ out, int K, int N) {
  __shared__ float tile[64][65];  // tile[n][k]
  int n0 = blockIdx.x * 64, k0 = blockIdx.y * 64;
  const float* src = in + (size_t)blockIdx.z * K * N;
  ushort* dst = out + (size_t)blockIdx.z * K * N;
  int t = threadIdx.x;
  int lk = t >> 4;           // 0..15 (k-row per pass)
  int ln4 = (t & 15) * 4;    // n-quad
#pragma unroll
  for (int j = 0; j < 4; ++j) {
    int k = lk + j * 16;
    float4 v = *(const float4*)(src + (size_t)(k0 + k) * N + n0 + ln4);
    tile[ln4 + 0][k] = v.x;
    tile[ln4 + 1][k] = v.y;
    tile[ln4 + 2][k] = v.z;
    tile[ln4 + 3][k] = v.w;
  }
  __syncthreads();
  int kc = (t & 15) * 4;     // k-quad
  int nb = t >> 4;           // 0..15
#pragma unroll
  for (int j = 0; j < 4; ++j) {
    int nn = nb + j * 16;
    ushort4 o;
    o.x = f2bf(tile[nn][kc + 0]);
    o.y = f2bf(tile[nn][kc + 1]);
    o.z = f2bf(tile[nn][kc + 2]);
    o.w = f2bf(tile[nn][kc + 3]);
    *(ushort4*)(dst + (size_t)(n0 + nn) * K + k0 + kc) = o;
  }
}

// ---------------- routing (counting sort by expert) ----------------

__global__ void count_k(const int* __restrict__ d, int* __restrict__ counts) {
  int i = blockIdx.x * 256 + threadIdx.x;
  if (i < B_SZ) atomicAdd(&counts[d[i]], 1);
}

__global__ void build_k(const int* __restrict__ counts, int* __restrict__ catalog,
                        int* __restrict__ poff, int* __restrict__ cursors) {
  if (threadIdx.x == 0) {
    int off = 0;  // in tiles
    for (int e = 0; e < NE; ++e) {
      poff[e] = off * 128;
      int nt = (counts[e] + 127) >> 7;
      for (int i = 0; i < nt; ++i) catalog[off + i] = e;
      off += nt;
      cursors[e] = 0;
    }
    for (int i = off; i < MAX_TILES; ++i) catalog[i] = -1;
  }
}

__global__ void scatter_k(const int* __restrict__ d, const int* __restrict__ poff,
                          int* __restrict__ cursors, int* __restrict__ perm) {
  int i = blockIdx.x * 256 + threadIdx.x;
  if (i < B_SZ) {
    int e = d[i];
    int p = atomicAdd(&cursors[e], 1);
    perm[poff[e] + p] = i;
  }
}

__global__ void init_out_k(const int* __restrict__ d, const float* __restrict__ b2,
                           float* __restrict__ out) {
  int i = blockIdx.x * 256 + threadIdx.x;
  if (i < B_SZ) out[i] = b2[d[i]];  // spec_b2[e][0]
}

// ---------------- m97-style bf16 GEMM: C = act(A @ Bt^T + bias) ----------------
// A: [M][K] bf16, Bt: [N][K] bf16, C: [M][N] bf16. 128x128 tile, BK=64,
// 256 thr = 4 waves in 2x2, each wave 64x64 via 4x4 mfma_f32_16x16x32_bf16.
// LDS rows XOR-swizzled in 16B chunks so frag ds_read_b128 is 2-way (free).
// 1-D grid with XCD-aware swizzle: all N-blocks of one A row-panel get ids
// congruent mod 8 -> same XCD L2 -> the panel is fetched from HBM once.
// Requires (M/128) % 8 == 0 and N/128 a power of two (lognx).

template <int RELU>
__global__ __launch_bounds__(256, 2) void gemm_bias(
    const ushort* __restrict__ A, const ushort* __restrict__ Bt,
    const float* __restrict__ bias, ushort* __restrict__ C,
    int M, int N, int K, int lognx) {
  __shared__ __align__(16) ushort lA[128 * 64];
  __shared__ __align__(16) ushort lB[128 * 64];
  const int t = threadIdx.x;
  const int h = blockIdx.x;
  const int g = h >> 3;
  const int nx = 1 << lognx;
  const int by = (h & 7) + ((g >> lognx) << 3);
  const int bx = g & (nx - 1);
  const int m0 = by * 128, n0 = bx * 128;
  const int w = t >> 6, lane = t & 63;
  const int wm = (w >> 1) * 64, wn = (w & 1) * 64;
  const int q = lane >> 4, rl = lane & 15;

  f32x4 acc[4][4];
#pragma unroll
  for (int mi = 0; mi < 4; ++mi)
#pragma unroll
    for (int ni = 0; ni < 4; ++ni) acc[mi][ni] = 0.0f;

  const int row_s = t >> 3;  // staging row within 32-row round
  const int pch_s = t & 7;   // physical 16B chunk within row

  for (int k0 = 0; k0 < K; k0 += 64) {
    __syncthreads();
#pragma unroll
    for (int j = 0; j < 4; ++j) {
      int row = j * 32 + row_s;
      int gch = pch_s ^ (row & 7);
      gl_lds16(A + (size_t)(m0 + row) * K + k0 + gch * 8, lA + j * 2048 + w * 512);
      gl_lds16(Bt + (size_t)(n0 + row) * K + k0 + gch * 8, lB + j * 2048 + w * 512);
    }
    __syncthreads();
#pragma unroll
    for (int kk = 0; kk < 2; ++kk) {
      bf16x8 af[4], bfr[4];
#pragma unroll
      for (int i = 0; i < 4; ++i) {
        int pc = (kk * 4 + q) ^ (rl & 7);
        af[i]  = __builtin_bit_cast(bf16x8, *(const int4*)(lA + (wm + i * 16 + rl) * 64 + pc * 8));
        bfr[i] = __builtin_bit_cast(bf16x8, *(const int4*)(lB + (wn + i * 16 + rl) * 64 + pc * 8));
      }
#pragma unroll
      for (int mi = 0; mi < 4; ++mi)
#pragma unroll
        for (int ni = 0; ni < 4; ++ni)
          acc[mi][ni] = __builtin_amdgcn_mfma_f32_16x16x32_bf16(af[mi], bfr[ni], acc[mi][ni], 0, 0, 0);
    }
  }

  // epilogue: C/D layout col=lane&15, row=(lane>>4)*4+reg (m89-verified)
  float bv[4];
#pragma unroll
  for (int ni = 0; ni < 4; ++ni) bv[ni] = bias[n0 + wn + ni * 16 + rl];
#pragma unroll
  for (int mi = 0; mi < 4; ++mi) {
    int rg = m0 + wm + mi * 16 + q * 4;
#pragma unroll
    for (int r = 0; r < 4; ++r) {
#pragma unroll
      for (int ni = 0; ni < 4; ++ni) {
        float v = acc[mi][ni][r] + bv[ni];
        if (RELU) v = fmaxf(v, 0.0f);
        C[(size_t)(rg + r) * N + n0 + wn + ni * 16 + rl] = f2bf(v);
      }
    }
  }
}

// ---------------- fused expert stage ----------------
// Block = (row-tile of 128 gathered rows of one expert) x (128-col chunk of SPEC_H).
// Computes h = relu(Z[rows] @ W1t[e]^T + b1[e]) for its 128x128 tile in regs,
// immediately reduces y_partial = h . w2[e][cols], atomicAdds into out[rows].
// Note: grid x-stride 136 is 0 mod 8, so all col-blocks of one row-tile already
// land on the same XCD under %8 round-robin (kept as-is deliberately).
__global__ __launch_bounds__(256, 2) void expert_fused(
    const ushort* __restrict__ Z, const ushort* __restrict__ W1t,
    const float* __restrict__ b1, const float* __restrict__ w2,
    const int* __restrict__ perm, const int* __restrict__ catalog,
    float* __restrict__ out) {
  int e = catalog[blockIdx.x];
  if (e < 0) return;
  __shared__ __align__(16) ushort lA[128 * 64];
  __shared__ __align__(16) ushort lB[128 * 64];
  __shared__ int perml[128];
  __shared__ float ysum[128];
  const int t = threadIdx.x;
  if (t < 128) {
    perml[t] = perm[blockIdx.x * 128 + t];
    ysum[t] = 0.0f;
  }
  __syncthreads();

  const int n0 = blockIdx.y * 128;
  const ushort* Bt = W1t + (size_t)e * SPEC_H * HID;
  const float* b1e = b1 + (size_t)e * SPEC_H;
  const float* w2e = w2 + (size_t)e * SPEC_H;
  const int w = t >> 6, lane = t & 63;
  const int wm = (w >> 1) * 64, wn = (w & 1) * 64;
  const int q = lane >> 4, rl = lane & 15;

  f32x4 acc[4][4];
#pragma unroll
  for (int mi = 0; mi < 4; ++mi)
#pragma unroll
    for (int ni = 0; ni < 4; ++ni) acc[mi][ni] = 0.0f;

  const int row_s = t >> 3;
  const int pch_s = t & 7;

  for (int k0 = 0; k0 < HID; k0 += 64) {
    __syncthreads();
#pragma unroll
    for (int j = 0; j < 4; ++j) {
      int row = j * 32 + row_s;
      int gch = pch_s ^ (row & 7);
      int zr = perml[row];
      zr = zr < 0 ? 0 : zr;  // pad rows read row 0; discarded later
      gl_lds16(Z + (size_t)zr * HID + k0 + gch * 8, lA + j * 2048 + w * 512);
      gl_lds16(Bt + (size_t)(n0 + row) * HID + k0 + gch * 8, lB + j * 2048 + w * 512);
    }
    __syncthreads();
#pragma unroll
    for (int kk = 0; kk < 2; ++kk) {
      bf16x8 af[4], bfr[4];
#pragma unroll
      for (int i = 0; i < 4; ++i) {
        int pc = (kk * 4 + q) ^ (rl & 7);
        af[i]  = __builtin_bit_cast(bf16x8, *(const int4*)(lA + (wm + i * 16 + rl) * 64 + pc * 8));
        bfr[i] = __builtin_bit_cast(bf16x8, *(const int4*)(lB + (wn + i * 16 + rl) * 64 + pc * 8));
      }
#pragma unroll
      for (int mi = 0; mi < 4; ++mi)
#pragma unroll
        for (int ni = 0; ni < 4; ++ni)
          acc[mi][ni] = __builtin_amdgcn_mfma_f32_16x16x32_bf16(af[mi], bfr[ni], acc[mi][ni], 0, 0, 0);
    }
  }

  // epilogue: h = relu(acc + b1), partial y = sum_n h * w2
  float w2v[4], b1v[4];
#pragma unroll
  for (int ni = 0; ni < 4; ++ni) {
    int n = n0 + wn + ni * 16 + rl;
    w2v[ni] = w2e[n];
    b1v[ni] = b1e[n];
  }
#pragma unroll
  for (int mi = 0; mi < 4; ++mi) {
#pragma unroll
    for (int r = 0; r < 4; ++r) {
      float p = 0.0f;
#pragma unroll
      for (int ni = 0; ni < 4; ++ni) {
        float h = acc[mi][ni][r] + b1v[ni];
        h = fmaxf(h, 0.0f);
        p += h * w2v[ni];
      }
      // reduce across the 16 lanes holding the 16 cols of this row
      p += __shfl_xor(p, 1);
      p += __shfl_xor(p, 2);
      p += __shfl_xor(p, 4);
      p += __shfl_xor(p, 8);
      if (rl == 0) atomicAdd(&ysum[wm + mi * 16 + q * 4 + r], p);
    }
  }
  __syncthreads();
  if (t < 128) {
    int orow = perml[t];
    if (orow >= 0) atomicAdd(&out[orow], ysum[t]);
  }
}

// ---------------- host ----------------

extern "C" void kernel_launch(void* const* d_in, const int* in_sizes, int n_in,
                              void* d_out, int out_size, void* d_ws, size_t ws_size,
                              hipStream_t stream) {
  const float* x   = (const float*)d_in[0];
  const int*   d   = (const int*)d_in[1];
  const float* eW0 = (const float*)d_in[2];
  const float* eb0 = (const float*)d_in[3];
  const float* eW1 = (const float*)d_in[4];
  const float* eb1 = (const float*)d_in[5];
  const float* eW2 = (const float*)d_in[6];
  const float* eb2 = (const float*)d_in[7];
  const float* sW1 = (const float*)d_in[8];
  const float* sb1 = (const float*)d_in[9];
  const float* sW2 = (const float*)d_in[10];
  const float* sb2 = (const float*)d_in[11];
  float* out = (float*)d_out;

  // Adaptive encoder chunk: pick the largest that fits ws_size.
  // Fixed part: weights bf16 (48 MiB) + Zb (32 MiB) + routing (~0.1 MiB).
  // Per-chunk: xb_c + z1_c + z2_c = CH * (1024+2048+2048)*2 = CH*10240 bytes.
  const size_t fixed = ((size_t)(4 + 8 + 4 + 32 + 32) << 20) + (1 << 20);
  int CH = 4096;
  if (ws_size >= fixed + (size_t)16384 * 10240) CH = 16384;       // ~241 MiB
  else if (ws_size >= fixed + (size_t)8192 * 10240) CH = 8192;    // ~164 MiB

  char* p = (char*)d_ws;
  ushort* W0t  = (ushort*)p; p += (size_t)IN_DIM * H1 * 2;        //  4 MiB
  ushort* W1t  = (ushort*)p; p += (size_t)H1 * H2 * 2;            //  8 MiB
  ushort* W2t  = (ushort*)p; p += (size_t)H2 * HID * 2;           //  4 MiB
  ushort* sW1t = (ushort*)p; p += (size_t)NE * HID * SPEC_H * 2;  // 32 MiB
  ushort* Zb   = (ushort*)p; p += (size_t)B_SZ * HID * 2;         // 32 MiB
  int* counts  = (int*)p; p += 64;
  int* cursors = (int*)p; p += 64;
  int* poff    = (int*)p; p += 64;
  int* catalog = (int*)p; p += 1024;                    // >= MAX_TILES ints
  int* perm    = (int*)p; p += (size_t)MAX_TILES * 128 * 4;
  p = (char*)(((uintptr_t)p + 255) & ~(uintptr_t)255);
  ushort* xb_c = (ushort*)p; p += (size_t)CH * IN_DIM * 2;
  ushort* z1_c = (ushort*)p; p += (size_t)CH * H1 * 2;
  ushort* z2_c = (ushort*)p; p += (size_t)CH * H2 * 2;

  hipMemsetAsync(counts, 0, 64, stream);
  hipMemsetAsync(perm, 0xFF, (size_t)MAX_TILES * 128 * 4, stream);  // -1 = pad

  // routing (independent of encoder; cheap)
  count_k<<<B_SZ / 256, 256, 0, stream>>>(d, counts);
  build_k<<<1, 64, 0, stream>>>(counts, catalog, poff, cursors);
  scatter_k<<<B_SZ / 256, 256, 0, stream>>>(d, poff, cursors, perm);
  init_out_k<<<B_SZ / 256, 256, 0, stream>>>(d, sb2, out);

  // weight transposes to bf16 [N][K] (once)
  transpose_cast<<<dim3(H1 / 64, IN_DIM / 64, 1), 256, 0, stream>>>(eW0, W0t, IN_DIM, H1);
  transpose_cast<<<dim3(H2 / 64, H1 / 64, 1), 256, 0, stream>>>(eW1, W1t, H1, H2);
  transpose_cast<<<dim3(HID / 64, H2 / 64, 1), 256, 0, stream>>>(eW2, W2t, H2, HID);
  transpose_cast<<<dim3(SPEC_H / 64, HID / 64, NE), 256, 0, stream>>>(sW1, sW1t, HID, SPEC_H);

  // encoder: x -> z1 -> z2 -> Zb (chunked only if workspace forces it)
  for (int c = 0; c < B_SZ; c += CH) {
    cast_f32_bf16<<<(CH * IN_DIM) / 1024, 256, 0, stream>>>(
        x + (size_t)c * IN_DIM, xb_c, CH * IN_DIM);
    gemm_bias<1><<<(CH / 128) * (H1 / 128), 256, 0, stream>>>(
        xb_c, W0t, eb0, z1_c, CH, H1, IN_DIM, 4);
    gemm_bias<1><<<(CH / 128) * (H2 / 128), 256, 0, stream>>>(
        z1_c, W1t, eb1, z2_c, CH, H2, H1, 4);
    gemm_bias<0><<<(CH / 128) * (HID / 128), 256, 0, stream>>>(
        z2_c, W2t, eb2, Zb + (size_t)c * HID, CH, HID, H2, 3);
  }

  // fused expert stage on full routed batch
  expert_fused<<<dim3(MAX_TILES, SPEC_H / 128), 256, 0, stream>>>(
      Zb, sW1t, sb1, sW2, perm, catalog, out);
}